// Round 1
// baseline (481.115 us; speedup 1.0000x reference)
//
#include <hip/hip_runtime.h>

// Problem constants (match reference)
constexpr int B = 128;
constexpr int N = 16384;
constexpr int H = 512;
constexpr int W = 512;
constexpr int HW = H * W;                        // 262144
constexpr long long TOT = (long long)B * HW;     // 33554432 pixels
constexpr int TOT4 = (int)(TOT / 4);             // float4 count: 8388608
constexpr int NPTS = B * N;                      // 2097152 points
constexpr int NGROUPS = NPTS / 4;                // 524288 (4 points / thread)

constexpr int RED_BLOCKS = 2048;

// ---------------------------------------------------------------------------
// Kernel 1: img = -targets   (so after splat, img holds (splat - target))
// ---------------------------------------------------------------------------
__global__ void __launch_bounds__(256) k_init(const float4* __restrict__ tgt,
                                              float4* __restrict__ img) {
    int i = blockIdx.x * blockDim.x + threadIdx.x;
    int stride = gridDim.x * blockDim.x;
    for (; i < TOT4; i += stride) {
        float4 t = tgt[i];
        img[i] = make_float4(-t.x, -t.y, -t.z, -t.w);
    }
}

// ---------------------------------------------------------------------------
// Kernel 2: bilinear splat, 4 points per thread (48B contiguous per thread)
// ---------------------------------------------------------------------------
__device__ __forceinline__ void splat_one(float px, float py, float inten,
                                          float* __restrict__ img) {
    float x = fminf(fmaxf(px, 0.0f), (float)(W - 1));
    float y = fminf(fmaxf(py, 0.0f), (float)(H - 1));
    float x0f = floorf(x);
    float y0f = floorf(y);
    float fx = x - x0f;
    float fy = y - y0f;
    int x0 = (int)x0f;
    int y0 = (int)y0f;
    int x1 = min(x0 + 1, W - 1);
    int y1 = min(y0 + 1, H - 1);
    float wx1 = fx, wx0 = 1.0f - fx;
    float wy1 = fy, wy0 = 1.0f - fy;
    unsafeAtomicAdd(&img[y0 * W + x0], inten * wx0 * wy0);
    unsafeAtomicAdd(&img[y0 * W + x1], inten * wx1 * wy0);
    unsafeAtomicAdd(&img[y1 * W + x0], inten * wx0 * wy1);
    unsafeAtomicAdd(&img[y1 * W + x1], inten * wx1 * wy1);
}

__global__ void __launch_bounds__(256) k_splat(const float4* __restrict__ pts,
                                               float* __restrict__ img) {
    int tid = blockIdx.x * blockDim.x + threadIdx.x;   // one group of 4 points
    if (tid >= NGROUPS) return;
    float4 a = pts[tid * 3 + 0];   // x0 y0 i0 x1
    float4 b = pts[tid * 3 + 1];   // y1 i1 x2 y2
    float4 c = pts[tid * 3 + 2];   // i2 x3 y3 i3

    // frame index: 4 points per group, N=16384 divisible by 4 -> same frame
    int frame = tid >> 12;         // (tid*4) / 16384
    float* fimg = img + (size_t)frame * HW;

    splat_one(a.x, a.y, a.z, fimg);
    splat_one(a.w, b.x, b.y, fimg);
    splat_one(b.z, b.w, c.x, fimg);
    splat_one(c.y, c.z, c.w, fimg);
}

// ---------------------------------------------------------------------------
// Kernel 3: partial sum of squares (double accumulators)
// ---------------------------------------------------------------------------
__global__ void __launch_bounds__(256) k_reduce(const float4* __restrict__ img,
                                                double* __restrict__ partials) {
    int i = blockIdx.x * blockDim.x + threadIdx.x;
    int stride = gridDim.x * blockDim.x;
    double acc = 0.0;
    for (; i < TOT4; i += stride) {
        float4 v = img[i];
        acc += (double)(v.x * v.x + v.y * v.y) + (double)(v.z * v.z + v.w * v.w);
    }
    // wave (64-lane) reduction
    for (int off = 32; off > 0; off >>= 1)
        acc += __shfl_down(acc, off, 64);
    __shared__ double sacc[4];
    int lane = threadIdx.x & 63;
    int wave = threadIdx.x >> 6;
    if (lane == 0) sacc[wave] = acc;
    __syncthreads();
    if (threadIdx.x == 0) {
        double s = sacc[0] + sacc[1] + sacc[2] + sacc[3];
        partials[blockIdx.x] = s;
    }
}

// ---------------------------------------------------------------------------
// Kernel 4: final reduce of RED_BLOCKS partials -> mean -> d_out[0] (float)
// ---------------------------------------------------------------------------
__global__ void __launch_bounds__(256) k_final(const double* __restrict__ partials,
                                               float* __restrict__ out) {
    double acc = 0.0;
    for (int i = threadIdx.x; i < RED_BLOCKS; i += 256)
        acc += partials[i];
    for (int off = 32; off > 0; off >>= 1)
        acc += __shfl_down(acc, off, 64);
    __shared__ double sacc[4];
    int lane = threadIdx.x & 63;
    int wave = threadIdx.x >> 6;
    if (lane == 0) sacc[wave] = acc;
    __syncthreads();
    if (threadIdx.x == 0) {
        double s = sacc[0] + sacc[1] + sacc[2] + sacc[3];
        out[0] = (float)(s / (double)TOT);
    }
}

// ---------------------------------------------------------------------------
extern "C" void kernel_launch(void* const* d_in, const int* in_sizes, int n_in,
                              void* d_out, int out_size, void* d_ws, size_t ws_size,
                              hipStream_t stream) {
    const float* pts = (const float*)d_in[0];     // [B, N, 3]
    const float* tgt = (const float*)d_in[1];     // [B, H, W]
    float* out = (float*)d_out;

    // workspace layout: [ image: TOT floats (128 MiB) | partials: RED_BLOCKS doubles ]
    float* img = (float*)d_ws;
    double* partials = (double*)((char*)d_ws + (size_t)TOT * sizeof(float));

    k_init<<<2048, 256, 0, stream>>>((const float4*)tgt, (float4*)img);
    k_splat<<<(NGROUPS + 255) / 256, 256, 0, stream>>>((const float4*)pts, img);
    k_reduce<<<RED_BLOCKS, 256, 0, stream>>>((const float4*)img, partials);
    k_final<<<1, 256, 0, stream>>>(partials, out);
}

// Round 2
// 88.294 us; speedup vs baseline: 5.4490x; 5.4490x over previous
//
#include <hip/hip_runtime.h>

// Problem constants (match reference)
constexpr int B = 128;
constexpr int N = 16384;
constexpr int H = 512;
constexpr int W = 512;
constexpr int HW = H * W;                        // 262144
constexpr long long TOT = (long long)B * HW;     // 33554432 pixels

constexpr int TROWS = 32;                        // rows per tile (64 KiB LDS)
constexpr int NTILES = H / TROWS;                // 16 tiles per frame
constexpr int NBLOCKS = B * NTILES;              // 2048 blocks
constexpr int GROUPS_PER_FRAME = N / 4;          // 4096 groups of 4 points
constexpr int F4_PER_FRAME = N * 3 / 4;          // 12288 float4 per frame

// ---------------------------------------------------------------------------
// Fused kernel: per-(frame,tile) LDS splat + squared-diff partial reduce.
// No global image, no global atomics.
// ---------------------------------------------------------------------------
__device__ __forceinline__ void splat_one_tile(float px, float py, float inten,
                                               float* __restrict__ tile, int r0) {
    float x = fminf(fmaxf(px, 0.0f), (float)(W - 1));
    float y = fminf(fmaxf(py, 0.0f), (float)(H - 1));
    float x0f = floorf(x);
    float y0f = floorf(y);
    float fx = x - x0f;
    float fy = y - y0f;
    int x0 = (int)x0f;
    int y0 = (int)y0f;
    int x1 = min(x0 + 1, W - 1);
    int y1 = min(y0 + 1, H - 1);
    int ra = y0 - r0;              // row of top pair, tile-relative
    int rb = y1 - r0;              // row of bottom pair
    float w00 = inten * (1.0f - fx) * (1.0f - fy);
    float w01 = inten * fx * (1.0f - fy);
    float w10 = inten * (1.0f - fx) * fy;
    float w11 = inten * fx * fy;
    if ((unsigned)ra < (unsigned)TROWS) {
        atomicAdd(&tile[ra * W + x0], w00);
        atomicAdd(&tile[ra * W + x1], w01);
    }
    if ((unsigned)rb < (unsigned)TROWS) {
        atomicAdd(&tile[rb * W + x0], w10);
        atomicAdd(&tile[rb * W + x1], w11);
    }
}

__global__ void __launch_bounds__(256) k_fused(const float4* __restrict__ pts,
                                               const float* __restrict__ tgt,
                                               double* __restrict__ partials) {
    __shared__ float tile[TROWS * W];            // 16384 floats = 64 KiB exactly

    int bid = blockIdx.x;
    int frame = bid >> 4;                        // NTILES = 16
    int t = bid & (NTILES - 1);
    int r0 = t * TROWS;

    // ---- zero the LDS tile ----
    float4* t4 = (float4*)tile;
    for (int i = threadIdx.x; i < TROWS * W / 4; i += 256)
        t4[i] = make_float4(0.f, 0.f, 0.f, 0.f);
    __syncthreads();

    // ---- splat this frame's points whose rows land in [r0, r0+TROWS) ----
    const float4* fp = pts + (size_t)frame * F4_PER_FRAME;
    for (int g = threadIdx.x; g < GROUPS_PER_FRAME; g += 256) {
        float4 a = fp[g * 3 + 0];    // x0 y0 i0 x1
        float4 b = fp[g * 3 + 1];    // y1 i1 x2 y2
        float4 c = fp[g * 3 + 2];    // i2 x3 y3 i3
        splat_one_tile(a.x, a.y, a.z, tile, r0);
        splat_one_tile(a.w, b.x, b.y, tile, r0);
        splat_one_tile(b.z, b.w, c.x, tile, r0);
        splat_one_tile(c.y, c.z, c.w, tile, r0);
    }
    __syncthreads();

    // ---- squared diff against target tile, double accumulation ----
    const float4* tg = (const float4*)(tgt + (size_t)frame * HW + (size_t)r0 * W);
    double acc = 0.0;
    for (int i = threadIdx.x; i < TROWS * W / 4; i += 256) {
        float4 tv = tg[i];
        float4 sv = t4[i];
        float d0 = sv.x - tv.x;
        float d1 = sv.y - tv.y;
        float d2 = sv.z - tv.z;
        float d3 = sv.w - tv.w;
        acc += (double)(d0 * d0 + d1 * d1) + (double)(d2 * d2 + d3 * d3);
    }

    // ---- block reduction (reuse tile LDS as scratch after a sync) ----
    for (int off = 32; off > 0; off >>= 1)
        acc += __shfl_down(acc, off, 64);
    __syncthreads();                             // tile reads all done
    double* sacc = (double*)tile;
    int lane = threadIdx.x & 63;
    int wave = threadIdx.x >> 6;
    if (lane == 0) sacc[wave] = acc;
    __syncthreads();
    if (threadIdx.x == 0)
        partials[bid] = sacc[0] + sacc[1] + sacc[2] + sacc[3];
}

// ---------------------------------------------------------------------------
// Final reduce of NBLOCKS partials -> mean -> d_out[0] (float)
// ---------------------------------------------------------------------------
__global__ void __launch_bounds__(256) k_final(const double* __restrict__ partials,
                                               float* __restrict__ out) {
    double acc = 0.0;
    for (int i = threadIdx.x; i < NBLOCKS; i += 256)
        acc += partials[i];
    for (int off = 32; off > 0; off >>= 1)
        acc += __shfl_down(acc, off, 64);
    __shared__ double sacc[4];
    int lane = threadIdx.x & 63;
    int wave = threadIdx.x >> 6;
    if (lane == 0) sacc[wave] = acc;
    __syncthreads();
    if (threadIdx.x == 0) {
        double s = sacc[0] + sacc[1] + sacc[2] + sacc[3];
        out[0] = (float)(s / (double)TOT);
    }
}

// ---------------------------------------------------------------------------
extern "C" void kernel_launch(void* const* d_in, const int* in_sizes, int n_in,
                              void* d_out, int out_size, void* d_ws, size_t ws_size,
                              hipStream_t stream) {
    const float* pts = (const float*)d_in[0];     // [B, N, 3]
    const float* tgt = (const float*)d_in[1];     // [B, H, W]
    float* out = (float*)d_out;

    double* partials = (double*)d_ws;             // NBLOCKS doubles = 16 KiB

    k_fused<<<NBLOCKS, 256, 0, stream>>>((const float4*)pts, tgt, partials);
    k_final<<<1, 256, 0, stream>>>(partials, out);
}